// Round 1
// baseline (784.908 us; speedup 1.0000x reference)
//
#include <hip/hip_runtime.h>

// CTC loss forward (sum reduction), faithful to the JAX reference.
// T=2048, N=256, C=128, L=200, S=2L+1=401.
// One workgroup (512 threads) per batch sample; alpha recursion in LDS,
// log2-domain math (v_exp_f32/v_log_f32 are base-2 native).
// Emission rows staged via global_load_lds 8-deep ring, counted vmcnt,
// raw s_barrier (avoids the compiler's vmcnt(0) drain at __syncthreads).

#define TT 2048
#define NN 256
#define CC 128
#define LL 200
#define SS 401

#define K_LOG2E 1.4426950408889634f
#define NEGB   (-1.44e30f)   /* -1e30 * log2(e): NEG surrogate in log2 domain */

typedef const void __attribute__((address_space(1)))* gas_ptr;
typedef void __attribute__((address_space(3)))* las_ptr;

__global__ __launch_bounds__(512, 1)
void ctc_alpha(const float* __restrict__ pred,
               const int* __restrict__ target,
               const int* __restrict__ tlen,
               float* __restrict__ loss_ws)
{
    __shared__ float sA[2][SS + 2];   // [0..1] = NEG padding, state s at index s+2
    __shared__ float sRow[9][CC];     // 8-slot prefetch ring + 1 dummy slot

    const int tid = threadIdx.x;
    const int n   = blockIdx.x;
    const int NC  = NN * CC;

    // --- per-state constants (ext label, skip index) ---
    // Reference quirk: starts[0]=0, starts[n>0]=target_length[n-1] (NOT a cumsum).
    int lab   = 0;   // emission class: blank(0) at even s, label at odd s
    int a2idx = 0;   // LDS index for alpha[s-2]; 0 => NEG pad (skip not allowed)
    if (tid < SS && (tid & 1)) {
        const int start = (n == 0) ? 0 : tlen[n - 1];
        lab = target[start + (tid >> 1)];
        if (tid >= 3) {
            const int prev = target[start + (tid >> 1) - 1];
            if (lab != prev) a2idx = tid;   // alpha[s-2] lives at index (s-2)+2 = tid
        }
    }

    // --- init alpha0 (log2 domain) ---
    if (tid < 2) { sA[0][tid] = NEGB; sA[1][tid] = NEGB; }
    if (tid < SS) {
        float b0 = NEGB;
        if (tid < 2) b0 = K_LOG2E * pred[n * CC + lab];  // row t=0
        sA[0][tid + 2] = b0;
    }

    // Drain all prior (compiler-issued) global loads so manual vmcnt counting is exact.
    asm volatile("s_waitcnt vmcnt(0)" ::: "memory");

    // --- prologue: prefetch rows 1..7 into ring slots 1..7 ---
    if (tid < CC) {   // waves 0,1 fully active (wave-uniform predicate)
        for (int j = 1; j <= 7; ++j) {
            const float* src = pred + (size_t)j * NC + n * CC + tid;
            __builtin_amdgcn_global_load_lds((gas_ptr)src,
                                             (las_ptr)&sRow[j][tid & 64],
                                             4, 0, 0);
        }
    }
    asm volatile("s_waitcnt vmcnt(6)" ::: "memory");   // row 1 landed
    asm volatile("s_waitcnt lgkmcnt(0)" ::: "memory"); // sA init visible
    __builtin_amdgcn_s_barrier();
    asm volatile("" ::: "memory");

    const float* gp    = pred + (size_t)8 * NC + n * CC + tid;          // row 8
    const float* gLast = pred + (size_t)(TT - 1) * NC + n * CC + tid;   // dummy reload src

    for (int t = 1; t < TT; ++t) {
        // 1. issue prefetch of row t+7 (dummy into slot 8 past the end, keeps vmcnt uniform)
        if (tid < CC) {
            const int rt = t + 7;
            const float* src = (rt < TT) ? gp : gLast;
            const int  slot  = (rt < TT) ? (rt & 7) : 8;
            __builtin_amdgcn_global_load_lds((gas_ptr)src,
                                             (las_ptr)&sRow[slot][tid & 64],
                                             4, 0, 0);
            gp += NC;
        }

        // 2. alpha update: beta_new[s] = max3 + log2(sum 2^(bi-m)) + log2e*pred[t,n,ext[s]]
        const int cur = (t - 1) & 1;
        const int nxt = t & 1;
        if (tid < SS) {
            const float a0 = sA[cur][tid + 2];
            const float a1 = sA[cur][tid + 1];
            const float a2 = sA[cur][a2idx];
            const float sc = sRow[t & 7][lab];
            const float m  = fmaxf(fmaxf(a0, a1), a2);
            const float e  = __builtin_amdgcn_exp2f(a0 - m)
                           + __builtin_amdgcn_exp2f(a1 - m)
                           + __builtin_amdgcn_exp2f(a2 - m);
            sA[nxt][tid + 2] = m + __builtin_amdgcn_logf(e) + K_LOG2E * sc;
        }

        // 3. make LDS writes visible, ensure row t+1 landed, then barrier.
        asm volatile("s_waitcnt lgkmcnt(0)" ::: "memory");
        asm volatile("s_waitcnt vmcnt(6)" ::: "memory");
        __builtin_amdgcn_s_barrier();
        asm volatile("" ::: "memory");
    }

    // Drain outstanding (dummy) prefetches before kernel end — LDS gets reused.
    asm volatile("s_waitcnt vmcnt(0) lgkmcnt(0)" ::: "memory");

    if (tid == 0) {
        const float a = sA[(TT - 1) & 1][SS];       // beta[S-2]  (index S-2+2)
        const float b = sA[(TT - 1) & 1][SS + 1];   // beta[S-1]
        const float m = fmaxf(a, b);
        const float ls = m + __builtin_amdgcn_logf(__builtin_amdgcn_exp2f(a - m) +
                                                   __builtin_amdgcn_exp2f(b - m));
        loss_ws[n] = -ls * (1.0f / K_LOG2E);        // back to natural-log loss
    }
}

__global__ void ctc_reduce(const float* __restrict__ ws, float* __restrict__ out)
{
    const int tid = threadIdx.x;   // 256 threads, 4 waves
    float v = ws[tid];
    v += __shfl_down(v, 32);
    v += __shfl_down(v, 16);
    v += __shfl_down(v, 8);
    v += __shfl_down(v, 4);
    v += __shfl_down(v, 2);
    v += __shfl_down(v, 1);
    __shared__ float p[4];
    if ((tid & 63) == 0) p[tid >> 6] = v;
    __syncthreads();
    if (tid == 0) out[0] = (p[0] + p[1]) + (p[2] + p[3]);
}

extern "C" void kernel_launch(void* const* d_in, const int* in_sizes, int n_in,
                              void* d_out, int out_size, void* d_ws, size_t ws_size,
                              hipStream_t stream)
{
    const float* pred   = (const float*)d_in[0];
    const int*   target = (const int*)d_in[1];
    // d_in[2] = input_length: unused by the reference computation
    const int*   tlen   = (const int*)d_in[3];
    float* ws = (float*)d_ws;   // 256 floats of scratch

    ctc_alpha<<<NN, 512, 0, stream>>>(pred, target, tlen, ws);
    ctc_reduce<<<1, NN, 0, stream>>>(ws, (float*)d_out);
}

// Round 3
// 657.923 us; speedup vs baseline: 1.1930x; 1.1930x over previous
//
#include <hip/hip_runtime.h>

// CTC loss forward (sum reduction), faithful to the JAX reference.
// T=2048, N=256, C=128, L=200, S=2L+1=401.
// One WAVE (64 lanes) per sample: alpha kept in registers, 7 states/lane
// (lane l owns states 7l..7l+6; 448 >= 401, excess states benign).
// Cross-lane halo (states 7l-1, 7l-2) via ds_bpermute — NO barriers.
// Emission rows staged via global_load_lds 8-slot ring (2 dword loads/row,
// offset=0 ALWAYS — the offset immediate was the round-2 bug), counted
// vmcnt(12), prefetch issued at END of each step behind a memory fence.
// Log2 domain (v_exp_f32/v_log_f32 are base-2 native); skip mask folded
// into an additive penalty.

#define TT 2048
#define NN 256
#define CC 128
#define LL 200
#define SS 401

#define K_LOG2E 1.4426950408889634f
#define NEGB   (-1.44e30f)   /* -1e30 * log2(e) */
#define PEN    (-2.0e30f)    /* additive 'disallowed' penalty */

typedef const void __attribute__((address_space(1)))* gas_ptr;
typedef void __attribute__((address_space(3)))* las_ptr;

__device__ __forceinline__ float max3f(float a, float b, float c) {
    float r; asm("v_max3_f32 %0, %1, %2, %3" : "=v"(r) : "v"(a), "v"(b), "v"(c)); return r;
}
__device__ __forceinline__ float med3f(float a, float b, float c) {
    float r; asm("v_med3_f32 %0, %1, %2, %3" : "=v"(r) : "v"(a), "v"(b), "v"(c)); return r;
}
__device__ __forceinline__ float min3f(float a, float b, float c) {
    float r; asm("v_min3_f32 %0, %1, %2, %3" : "=v"(r) : "v"(a), "v"(b), "v"(c)); return r;
}

__global__ __launch_bounds__(64, 1)
void ctc_alpha(const float* __restrict__ pred,
               const int* __restrict__ target,
               const int* __restrict__ tlen,
               float* __restrict__ loss_ws)
{
    __shared__ float sRow[8][CC];          // emission-row prefetch ring
    float* sRowF = &sRow[0][0];

    const int lane = threadIdx.x;          // 64 threads = 1 wave
    const int n    = blockIdx.x;
    const int NC   = NN * CC;

    // ---- per-state constants: label class + skip penalty ----
    // Reference quirk: starts[0]=0, starts[n>0]=target_length[n-1] (not a cumsum).
    const int start = (n == 0) ? 0 : tlen[n - 1];
    int   lab[7];
    float pk[7];
#pragma unroll
    for (int k = 0; k < 7; ++k) {
        const int s = 7 * lane + k;
        int l = 0; float p = PEN;
        if (s & 1) {                       // non-blank position
            l = target[start + (s >> 1)];
            if (s >= 3) {
                const int prev = target[start + (s >> 1) - 1];
                if (l != prev) p = 0.0f;   // skip transition allowed
            }
        }
        if (s > SS - 1) { l = 0; p = PEN; }   // states beyond S: benign
        lab[k] = l;
        pk[k]  = p;
    }

    const float hpen  = (lane == 0) ? PEN : 0.0f;     // kills halo for lane 0
    const int   bpidx = ((lane - 1) & 63) * 4;        // ds_bpermute byte index

    // ---- alpha_0 (log2 domain) ----
    float al[2][7];
#pragma unroll
    for (int k = 0; k < 7; ++k) {
        const int s = 7 * lane + k;
        const float e0 = pred[n * CC + lab[k]];       // row t=0
        al[0][k] = (s < 2) ? K_LOG2E * e0 : NEGB;
        al[1][k] = NEGB;
    }

    // Drain compiler-issued loads so manual vmcnt counting is exact.
    asm volatile("s_waitcnt vmcnt(0)" ::: "memory");

    // ---- prologue: prefetch rows 1..7 into slots 1..7 (2 dword loads each,
    //      offset=0, second load advances the GLOBAL pointer by 64 floats) ----
#pragma unroll
    for (int j = 1; j <= 7; ++j) {
        const float* src = pred + (size_t)j * NC + n * CC + lane;
        __builtin_amdgcn_global_load_lds((gas_ptr)src,        (las_ptr)&sRow[j][0],  4, 0, 0);
        __builtin_amdgcn_global_load_lds((gas_ptr)(src + 64), (las_ptr)&sRow[j][64], 4, 0, 0);
    }

    const float* gp  = pred + (size_t)8 * NC + n * CC + lane;   // next row, classes 0..63
    const float* gp2 = gp + 64;                                 // classes 64..127

    // One time step. PH: phase 0..7 (t = 8b+1+PH; slot/parity compile-time).
    // VM: vmcnt immediate for "row t has landed". PREF: issue prefetch of t+7.
#define CTC_STEP(PH, VM, PREF)                                                      \
    {                                                                               \
        asm volatile("s_waitcnt vmcnt(%0)" :: "i"(VM) : "memory");                  \
        const int cur  = (PH) & 1, nxt = cur ^ 1;                                   \
        const int slot = ((PH) + 1) & 7;                                            \
        const float h1 = __int_as_float(__builtin_amdgcn_ds_bpermute(               \
                             bpidx, __float_as_int(al[cur][6]))) + hpen;            \
        const float h2 = __int_as_float(__builtin_amdgcn_ds_bpermute(               \
                             bpidx, __float_as_int(al[cur][5]))) + hpen;            \
        _Pragma("unroll")                                                           \
        for (int k = 0; k < 7; ++k) {                                               \
            const float a0 = al[cur][k];                                            \
            const float a1 = (k == 0) ? h1 : al[cur][k - 1];                        \
            const float a2 = ((k == 0) ? h2 : (k == 1) ? h1 : al[cur][k - 2]) + pk[k]; \
            const float sc = sRowF[slot * CC + lab[k]];                             \
            const float m   = max3f(a0, a1, a2);                                    \
            const float mid = med3f(a0, a1, a2);                                    \
            const float lo  = min3f(a0, a1, a2);                                    \
            const float e = 1.0f + __builtin_amdgcn_exp2f(mid - m)                  \
                                 + __builtin_amdgcn_exp2f(lo  - m);                 \
            al[nxt][k] = m + __builtin_amdgcn_logf(e) + K_LOG2E * sc;               \
        }                                                                           \
        asm volatile("" ::: "memory");                                              \
        if (PREF) {                                                                 \
            __builtin_amdgcn_global_load_lds((gas_ptr)gp,  (las_ptr)&sRow[(PH)&7][0],  4, 0, 0); \
            __builtin_amdgcn_global_load_lds((gas_ptr)gp2, (las_ptr)&sRow[(PH)&7][64], 4, 0, 0); \
            gp += NC; gp2 += NC;                                                    \
        }                                                                           \
    }

    // main loop: b=0..254 covers t = 1..2040, prefetching row t+7 (8..2047)
    for (int b = 0; b < 255; ++b) {
        CTC_STEP(0, 12, 1)
        CTC_STEP(1, 12, 1)
        CTC_STEP(2, 12, 1)
        CTC_STEP(3, 12, 1)
        CTC_STEP(4, 12, 1)
        CTC_STEP(5, 12, 1)
        CTC_STEP(6, 12, 1)
        CTC_STEP(7, 12, 1)
    }
    // epilogue: t = 2041..2047, no prefetch, draining vmcnt
    CTC_STEP(0, 12, 0)
    CTC_STEP(1, 10, 0)
    CTC_STEP(2,  8, 0)
    CTC_STEP(3,  6, 0)
    CTC_STEP(4,  4, 0)
    CTC_STEP(5,  2, 0)
    CTC_STEP(6,  0, 0)
#undef CTC_STEP

    // alpha_2047 lives in al[1]; states S-2=399, S-1=400 are lane 57, k=0/1.
    if (lane == 57) {
        const float a = al[1][0];
        const float b = al[1][1];
        const float m = fmaxf(a, b);
        const float ls = m + __builtin_amdgcn_logf(__builtin_amdgcn_exp2f(a - m) +
                                                   __builtin_amdgcn_exp2f(b - m));
        loss_ws[n] = -ls * (1.0f / K_LOG2E);   // back to natural log
    }
}

__global__ void ctc_reduce(const float* __restrict__ ws, float* __restrict__ out)
{
    const int tid = threadIdx.x;   // 256 threads, 4 waves
    float v = ws[tid];
    v += __shfl_down(v, 32);
    v += __shfl_down(v, 16);
    v += __shfl_down(v, 8);
    v += __shfl_down(v, 4);
    v += __shfl_down(v, 2);
    v += __shfl_down(v, 1);
    __shared__ float p[4];
    if ((tid & 63) == 0) p[tid >> 6] = v;
    __syncthreads();
    if (tid == 0) out[0] = (p[0] + p[1]) + (p[2] + p[3]);
}

extern "C" void kernel_launch(void* const* d_in, const int* in_sizes, int n_in,
                              void* d_out, int out_size, void* d_ws, size_t ws_size,
                              hipStream_t stream)
{
    const float* pred   = (const float*)d_in[0];
    const int*   target = (const int*)d_in[1];
    // d_in[2] = input_length: unused by the reference computation
    const int*   tlen   = (const int*)d_in[3];
    float* ws = (float*)d_ws;

    ctc_alpha<<<NN, 64, 0, stream>>>(pred, target, tlen, ws);
    ctc_reduce<<<1, NN, 0, stream>>>(ws, (float*)d_out);
}

// Round 4
// 514.540 us; speedup vs baseline: 1.5255x; 1.2787x over previous
//
#include <hip/hip_runtime.h>

// CTC loss forward (sum reduction), faithful to the JAX reference.
// T=2048, N=256, C=128, L=200, S=2L+1=401.
// One WAVE (64 lanes) per sample: alpha in registers, 7 states/lane
// (lane l owns states 7l..7l+6). Cross-lane halo via ds_bpermute,
// SOFTWARE-PIPELINED ONE STEP AHEAD (issued right after new al[5],al[6],
// consumed at the NEXT step's k=0,1 -> ~120cy DS latency fully hidden).
// Emission scores for step t+1 are ds_read from the LDS ring DURING step t
// into parity-indexed registers -> step t's lse3 chain touches only VGPRs.
// Ring: 8-slot global_load_lds, counted vmcnt(12), never drained in-loop.
// Log2 domain (v_exp_f32/v_log_f32 are base-2 native); skip mask folded
// into an additive penalty; lse3 uses max3/med3/min3 + "1.0 +" trick.

#define TT 2048
#define NN 256
#define CC 128
#define LL 200
#define SS 401

#define K_LOG2E 1.4426950408889634f
#define NEGB   (-1.44e30f)   /* -1e30 * log2(e) */
#define PEN    (-2.0e30f)    /* additive 'disallowed' penalty */

typedef const void __attribute__((address_space(1)))* gas_ptr;
typedef void __attribute__((address_space(3)))* las_ptr;

__device__ __forceinline__ float max3f(float a, float b, float c) {
    float r; asm("v_max3_f32 %0, %1, %2, %3" : "=v"(r) : "v"(a), "v"(b), "v"(c)); return r;
}
__device__ __forceinline__ float med3f(float a, float b, float c) {
    float r; asm("v_med3_f32 %0, %1, %2, %3" : "=v"(r) : "v"(a), "v"(b), "v"(c)); return r;
}
__device__ __forceinline__ float min3f(float a, float b, float c) {
    float r; asm("v_min3_f32 %0, %1, %2, %3" : "=v"(r) : "v"(a), "v"(b), "v"(c)); return r;
}

// log2-domain logsumexp3 + emission add: one term of exp-sum is exactly 1.
__device__ __forceinline__ float lse3(float a0, float a1, float a2, float sc) {
    const float m   = max3f(a0, a1, a2);
    const float mid = med3f(a0, a1, a2);
    const float lo  = min3f(a0, a1, a2);
    const float e = 1.0f + __builtin_amdgcn_exp2f(mid - m)
                         + __builtin_amdgcn_exp2f(lo  - m);
    return m + __builtin_amdgcn_logf(e) + K_LOG2E * sc;
}

__global__ __launch_bounds__(64, 1)
void ctc_alpha(const float* __restrict__ pred,
               const int* __restrict__ target,
               const int* __restrict__ tlen,
               float* __restrict__ loss_ws)
{
    __shared__ float sRow[8][CC];          // emission-row prefetch ring
    float* sRowF = &sRow[0][0];

    const int lane = threadIdx.x;          // 64 threads = 1 wave
    const int n    = blockIdx.x;
    const int NC   = NN * CC;

    // ---- per-state constants: label class + skip penalty ----
    // Reference quirk: starts[0]=0, starts[n>0]=target_length[n-1] (not a cumsum).
    const int start = (n == 0) ? 0 : tlen[n - 1];
    int   lab[7];
    float pk[7];
#pragma unroll
    for (int k = 0; k < 7; ++k) {
        const int s = 7 * lane + k;
        int l = 0; float p = PEN;
        if (s & 1) {                       // non-blank position
            l = target[start + (s >> 1)];
            if (s >= 3) {
                const int prev = target[start + (s >> 1) - 1];
                if (l != prev) p = 0.0f;   // skip transition allowed
            }
        }
        if (s > SS - 1) { l = 0; p = PEN; }   // states beyond S: benign
        lab[k] = l;
        pk[k]  = p;
    }

    const float hpen  = (lane == 0) ? PEN : 0.0f;     // kills halo for lane 0
    const int   bpidx = ((lane - 1) & 63) * 4;        // ds_bpermute byte index

    // ---- alpha_0 (log2 domain) ----
    float al[2][7];    // alpha, parity-indexed
    float scp[2][7];   // emission scores for step t, parity-indexed
    float h[2][2];     // halo (state 7l-1, 7l-2), parity-indexed
#pragma unroll
    for (int k = 0; k < 7; ++k) {
        const int s = 7 * lane + k;
        const float e0 = pred[n * CC + lab[k]];       // row t=0
        al[0][k] = (s < 2) ? K_LOG2E * e0 : NEGB;
    }

    // Drain compiler-issued loads so manual vmcnt counting is exact.
    asm volatile("s_waitcnt vmcnt(0)" ::: "memory");

    // ---- prologue: prefetch rows 1..7 into slots 1..7 (2 dword loads each) ----
#pragma unroll
    for (int j = 1; j <= 7; ++j) {
        const float* src = pred + (size_t)j * NC + n * CC + lane;
        __builtin_amdgcn_global_load_lds((gas_ptr)src,        (las_ptr)&sRow[j][0],  4, 0, 0);
        __builtin_amdgcn_global_load_lds((gas_ptr)(src + 64), (las_ptr)&sRow[j][64], 4, 0, 0);
    }

    // halo for step t=1 (from alpha_0)
    h[0][0] = __int_as_float(__builtin_amdgcn_ds_bpermute(bpidx, __float_as_int(al[0][6]))) + hpen;
    h[0][1] = __int_as_float(__builtin_amdgcn_ds_bpermute(bpidx, __float_as_int(al[0][5]))) + hpen;

    asm volatile("s_waitcnt vmcnt(12)" ::: "memory");   // row 1 resident
#pragma unroll
    for (int k = 0; k < 7; ++k) scp[0][k] = sRowF[1 * CC + lab[k]];   // row t=1

    const float* gp  = pred + (size_t)8 * NC + n * CC + lane;   // next row, classes 0..63
    const float* gp2 = gp + 64;                                 // classes 64..127

    // One time step, t = 8b+1+PH. VM: vmcnt immediate guaranteeing row t+1
    // resident. PREF: issue ring prefetch of row t+7 into slot PH&7.
    // NEXT: produce next step's halo + emission registers.
#define CTC_STEP(PH, VM, PREF, NEXT)                                                \
    {                                                                               \
        if (PREF) {                                                                 \
            __builtin_amdgcn_global_load_lds((gas_ptr)gp,  (las_ptr)&sRow[(PH)&7][0],  4, 0, 0); \
            __builtin_amdgcn_global_load_lds((gas_ptr)gp2, (las_ptr)&sRow[(PH)&7][64], 4, 0, 0); \
            gp += NC; gp2 += NC;                                                    \
        }                                                                           \
        asm volatile("s_waitcnt vmcnt(%0)" :: "i"(VM) : "memory");                  \
        const int cur = (PH) & 1, nxt = cur ^ 1;                                    \
        /* k=6,5 first: no halo dependency -> enables early bpermute issue */       \
        al[nxt][6] = lse3(al[cur][6], al[cur][5], al[cur][4] + pk[6], scp[cur][6]); \
        al[nxt][5] = lse3(al[cur][5], al[cur][4], al[cur][3] + pk[5], scp[cur][5]); \
        if (NEXT) {                                                                 \
            /* halo for step t+1: latency hidden under remaining VALU */            \
            h[nxt][0] = __int_as_float(__builtin_amdgcn_ds_bpermute(                \
                            bpidx, __float_as_int(al[nxt][6]))) + hpen;             \
            h[nxt][1] = __int_as_float(__builtin_amdgcn_ds_bpermute(                \
                            bpidx, __float_as_int(al[nxt][5]))) + hpen;             \
            /* emission gather for step t+1 (row t+1, slot (PH+2)&7) */             \
            _Pragma("unroll")                                                       \
            for (int k = 0; k < 7; ++k)                                             \
                scp[nxt][k] = sRowF[(((PH) + 2) & 7) * CC + lab[k]];                \
        }                                                                           \
        al[nxt][4] = lse3(al[cur][4], al[cur][3], al[cur][2] + pk[4], scp[cur][4]); \
        al[nxt][3] = lse3(al[cur][3], al[cur][2], al[cur][1] + pk[3], scp[cur][3]); \
        al[nxt][2] = lse3(al[cur][2], al[cur][1], al[cur][0] + pk[2], scp[cur][2]); \
        al[nxt][1] = lse3(al[cur][1], al[cur][0], h[cur][0]  + pk[1], scp[cur][1]); \
        al[nxt][0] = lse3(al[cur][0], h[cur][0], h[cur][1]   + pk[0], scp[cur][0]); \
    }

    // main loop: b=0..254 covers t=1..2040, prefetching rows 8..2047
    for (int b = 0; b < 255; ++b) {
        CTC_STEP(0, 12, 1, 1)
        CTC_STEP(1, 12, 1, 1)
        CTC_STEP(2, 12, 1, 1)
        CTC_STEP(3, 12, 1, 1)
        CTC_STEP(4, 12, 1, 1)
        CTC_STEP(5, 12, 1, 1)
        CTC_STEP(6, 12, 1, 1)
        CTC_STEP(7, 12, 1, 1)
    }
    // epilogue: t=2041..2047 (PH 0..6), no prefetch; outstanding drains 14->0
    CTC_STEP(0, 10, 0, 1)   // needs row 2042
    CTC_STEP(1,  8, 0, 1)
    CTC_STEP(2,  6, 0, 1)
    CTC_STEP(3,  4, 0, 1)
    CTC_STEP(4,  2, 0, 1)
    CTC_STEP(5,  0, 0, 1)   // needs row 2047
    CTC_STEP(6,  0, 0, 0)   // t=2047: final step, no next-step state
#undef CTC_STEP

    asm volatile("s_waitcnt vmcnt(0) lgkmcnt(0)" ::: "memory");

    // alpha_2047 lives in al[2047&1]=al[1]; states 399,400 are lane 57, k=0/1.
    if (lane == 57) {
        const float a = al[1][0];
        const float b = al[1][1];
        const float m = fmaxf(a, b);
        const float ls = m + __builtin_amdgcn_logf(__builtin_amdgcn_exp2f(a - m) +
                                                   __builtin_amdgcn_exp2f(b - m));
        loss_ws[n] = -ls * (1.0f / K_LOG2E);   // back to natural log
    }
}

__global__ void ctc_reduce(const float* __restrict__ ws, float* __restrict__ out)
{
    const int tid = threadIdx.x;   // 256 threads, 4 waves
    float v = ws[tid];
    v += __shfl_down(v, 32);
    v += __shfl_down(v, 16);
    v += __shfl_down(v, 8);
    v += __shfl_down(v, 4);
    v += __shfl_down(v, 2);
    v += __shfl_down(v, 1);
    __shared__ float p[4];
    if ((tid & 63) == 0) p[tid >> 6] = v;
    __syncthreads();
    if (tid == 0) out[0] = (p[0] + p[1]) + (p[2] + p[3]);
}

extern "C" void kernel_launch(void* const* d_in, const int* in_sizes, int n_in,
                              void* d_out, int out_size, void* d_ws, size_t ws_size,
                              hipStream_t stream)
{
    const float* pred   = (const float*)d_in[0];
    const int*   target = (const int*)d_in[1];
    // d_in[2] = input_length: unused by the reference computation
    const int*   tlen   = (const int*)d_in[3];
    float* ws = (float*)d_ws;

    ctc_alpha<<<NN, 64, 0, stream>>>(pred, target, tlen, ws);
    ctc_reduce<<<1, NN, 0, stream>>>(ws, (float*)d_out);
}

// Round 5
// 256.565 us; speedup vs baseline: 3.0593x; 2.0055x over previous
//
#include <hip/hip_runtime.h>

// CTC loss forward (sum), faithful to the JAX reference.
// T=2048, N=256, C=128, L=200, S=2L+1=401.
//
// One workgroup (4 waves = 256 threads) per sample. States split across
// waves: wave w owns states 128w .. 128w+127, 2 per lane (s0=2*idx even/blank,
// s1=2*idx+1 odd/label, idx = 64*w + lane). Within a wave the halo (state
// 2*idx-1 = prev lane's s1) comes from DPP wave_shr:1 (update_dpp merges the
// lane-0 boundary value via the 'old' operand). Across waves the recursion is
// strictly left->right, so sync is ONE-DIRECTIONAL: producer wave w writes its
// top state to bnd[w][t] each step + a monotonic block flag; consumer wave w+1
// runs ~2 blocks skewed, bulk-reads 8 boundaries one block ahead (latency
// hidden), spins only if it catches up. No barriers in the main loop.
// Emissions: direct global->register gather, 8-deep prefetch pipeline
// (rows stay L2-resident across the <=48-step wave skew).
// Log2 domain: v_exp_f32/v_log_f32 are base-2 native; blank states use lse2
// (skip transition structurally disallowed); skip mask folded into additive
// penalty pk1.

#define TT 2048
#define NN 256
#define CC 128
#define LL 200

#define K_LOG2E 1.4426950408889634f
#define K_LN2   0.6931471805599453f
#define NEGB   (-1.44e30f)   /* -1e30 * log2(e) */
#define PEN    (-2.0e30f)    /* additive 'disallowed' penalty */
#define NC4    131072u       /* NN*CC*4: byte stride between time rows */

__device__ __forceinline__ float max3f(float a, float b, float c) {
    float r; asm("v_max3_f32 %0, %1, %2, %3" : "=v"(r) : "v"(a), "v"(b), "v"(c)); return r;
}
__device__ __forceinline__ float med3f(float a, float b, float c) {
    float r; asm("v_med3_f32 %0, %1, %2, %3" : "=v"(r) : "v"(a), "v"(b), "v"(c)); return r;
}
__device__ __forceinline__ float min3f(float a, float b, float c) {
    float r; asm("v_min3_f32 %0, %1, %2, %3" : "=v"(r) : "v"(a), "v"(b), "v"(c)); return r;
}
__device__ __forceinline__ uint32_t umin32(uint32_t a, uint32_t b) { return a < b ? a : b; }

// log2-domain logsumexp3 + emission: max term's exp is exactly 1.
__device__ __forceinline__ float lse3(float a0, float a1, float a2, float sc) {
    const float m   = max3f(a0, a1, a2);
    const float mid = med3f(a0, a1, a2);
    const float lo  = min3f(a0, a1, a2);
    const float e = 1.0f + __builtin_amdgcn_exp2f(mid - m)
                         + __builtin_amdgcn_exp2f(lo  - m);
    return m + __builtin_amdgcn_logf(e) + K_LOG2E * sc;
}
__device__ __forceinline__ float lse2(float a, float b, float sc) {
    const float m  = fmaxf(a, b);
    const float lo = fminf(a, b);
    const float e = 1.0f + __builtin_amdgcn_exp2f(lo - m);
    return m + __builtin_amdgcn_logf(e) + K_LOG2E * sc;
}

__global__ __launch_bounds__(256, 1)
void ctc_alpha(const float* __restrict__ pred,
               const int* __restrict__ target,
               const int* __restrict__ tlen,
               float* __restrict__ loss_ws)
{
    __shared__ float bnd[5][TT];   // [w][t]: state 128w+127 after step t; row 4 = PEN (wave0 halo)
    __shared__ int   flags[8];     // [w] = blocks completed by wave w; [7] = INT_MAX dummy

    const int tid  = threadIdx.x;
    const int wid  = tid >> 6;
    const int lane = tid & 63;
    const int n    = blockIdx.x;

    if (tid < 8) flags[tid] = (tid >= 4) ? 0x7fffffff : 0;
    for (int i = tid; i < TT; i += 256) bnd[4][i] = PEN;

    // per-state constants. Reference quirk: starts[0]=0, starts[n>0]=tlen[n-1].
    const int start = (n == 0) ? 0 : tlen[n - 1];
    const int idx   = (wid << 6) | lane;     // s0 = 2*idx (blank), s1 = 2*idx+1 (label)
    int lab1 = 0; float pk1 = PEN;
    if (idx < LL) {
        lab1 = target[start + idx];
        if (idx >= 1 && lab1 != target[start + idx - 1]) pk1 = 0.0f;   // skip allowed
    }
    // idx >= LL: dead states (lab 0, skip disabled) — stay ~NEGB, never feed valid states.

    // ---- alpha_0 (log2 domain): only states 0,1 (idx==0, wave0) are live ----
    float al0, al1;
    {
        const float eB = pred[n * CC];
        const float eL = pred[n * CC + lab1];
        al0 = (idx == 0) ? K_LOG2E * eB : NEGB;
        al1 = (idx == 0) ? K_LOG2E * eL : NEGB;
    }
    if (lane == 63) bnd[wid][0] = al1;
    __syncthreads();   // flags/PEN-row/bnd[.][0] visible before any spin

    // ---- emission register pipeline, depth 8 (rows t .. t+7 resident) ----
    const char* pc = (const char*)pred;
    uint32_t offB = (uint32_t)(NN * CC + n * CC) * 4u;         // row 1, class 0
    uint32_t offL = offB + (uint32_t)lab1 * 4u;
    const uint32_t maxB = (2047u * (uint32_t)(NN * CC) + (uint32_t)(n * CC)) * 4u;
    const uint32_t maxL = maxB + (uint32_t)lab1 * 4u;
    float scB[8], scL[8];
#pragma unroll
    for (int ph = 0; ph < 8; ++ph) {                            // rows 1..8
        scB[ph] = *(const float*)(pc + offB);
        scL[ph] = *(const float*)(pc + offL);
        offB += NC4; offL += NC4;
    }

    const int     pidx  = (wid == 0) ? 7 : (wid - 1);
    const float*  bndC  = (wid == 0) ? bnd[4] : bnd[wid - 1];
    float*        bndW  = bnd[wid];
    volatile int* pflag = &flags[pidx];

    // prologue: boundaries for block 0 (bnd[0..7]) need producer flag >= 1
    int fval = 0;
    while (fval < 1) fval = *pflag;
    asm volatile("" ::: "memory");
    float bndv[8], bndN[8];
#pragma unroll
    for (int i = 0; i < 8; ++i) bndv[i] = bndC[i];
    fval = *pflag;   // refresh; consumed at next boundary (latency hidden)

    // One step, t = TBASE+1+PH. Halo h1 = prev lane's al1; lane0 <- bndv[PH]
    // via update_dpp's old operand (wave_shr:1 = 0x138).
#define CTC_STEP(PH, TBASE, PREF)                                              \
    {                                                                          \
        const int h1i = __builtin_amdgcn_update_dpp(                           \
            __float_as_int(bndv[PH]), __float_as_int(al1),                     \
            0x138, 0xf, 0xf, false);                                           \
        const float h1  = __int_as_float(h1i);                                 \
        const float na1 = lse3(al1, al0, h1 + pk1, scL[PH]);                   \
        const float na0 = lse2(al0, h1, scB[PH]);                              \
        al1 = na1; al0 = na0;                                                  \
        if (lane == 63) bndW[(TBASE) + 1 + (PH)] = al1;                        \
        if (PREF) {                                                            \
            scB[PH] = *(const float*)(pc + offB);                              \
            scL[PH] = *(const float*)(pc + offL);                              \
            offB = umin32(offB + NC4, maxB);                                   \
            offL = umin32(offL + NC4, maxL);                                   \
        }                                                                      \
    }

    // main loop: blocks b=0..254 cover t = 1..2040
    for (int b = 0; b < 255; ++b) {
        // ensure boundaries for NEXT block (bnd[8(b+1) .. 8(b+1)+7]) are written:
        // flag >= b+2; entering b=254 we pre-read the tail range -> need full 256.
        const int need = (b == 254) ? 256 : (b + 2);
        while (fval < need) fval = *pflag;
        asm volatile("" ::: "memory");
        const int rb = 8 * (b + 1);
#pragma unroll
        for (int i = 0; i < 8; ++i) bndN[i] = bndC[rb + i];
        fval = *pflag;   // refresh for next boundary

        const int tb = 8 * b;
        CTC_STEP(0, tb, 1) CTC_STEP(1, tb, 1) CTC_STEP(2, tb, 1) CTC_STEP(3, tb, 1)
        CTC_STEP(4, tb, 1) CTC_STEP(5, tb, 1) CTC_STEP(6, tb, 1) CTC_STEP(7, tb, 1)

        asm volatile("" ::: "memory");           // keep bnd writes before flag post
        if (lane == 0) *(volatile int*)&flags[wid] = b + 1;
#pragma unroll
        for (int i = 0; i < 8; ++i) bndv[i] = bndN[i];
    }

    // tail: t = 2041..2047 (bndv holds bnd[2040..2047], sc slots 0..6 hold rows 2041..2047)
    CTC_STEP(0, 2040, 0) CTC_STEP(1, 2040, 0) CTC_STEP(2, 2040, 0)
    CTC_STEP(3, 2040, 0) CTC_STEP(4, 2040, 0) CTC_STEP(5, 2040, 0)
    CTC_STEP(6, 2040, 0)
#undef CTC_STEP

    asm volatile("" ::: "memory");
    if (lane == 0) *(volatile int*)&flags[wid] = 256;   // tail boundaries posted

    // loss: states 399 (wave3 lane7 al1) and 400 (wave3 lane8 al0)
    const float A = __shfl(al1, 7, 64);
    const float B = __shfl(al0, 8, 64);
    if (wid == 3 && lane == 0) {
        const float m  = fmaxf(A, B);
        const float ls = m + __builtin_amdgcn_logf(
            __builtin_amdgcn_exp2f(A - m) + __builtin_amdgcn_exp2f(B - m));
        loss_ws[n] = -ls * K_LN2;   // back to natural log
    }
}

__global__ void ctc_reduce(const float* __restrict__ ws, float* __restrict__ out)
{
    const int tid = threadIdx.x;   // 256 threads, 4 waves
    float v = ws[tid];
    v += __shfl_down(v, 32);
    v += __shfl_down(v, 16);
    v += __shfl_down(v, 8);
    v += __shfl_down(v, 4);
    v += __shfl_down(v, 2);
    v += __shfl_down(v, 1);
    __shared__ float p[4];
    if ((tid & 63) == 0) p[tid >> 6] = v;
    __syncthreads();
    if (tid == 0) out[0] = (p[0] + p[1]) + (p[2] + p[3]);
}

extern "C" void kernel_launch(void* const* d_in, const int* in_sizes, int n_in,
                              void* d_out, int out_size, void* d_ws, size_t ws_size,
                              hipStream_t stream)
{
    const float* pred   = (const float*)d_in[0];
    const int*   target = (const int*)d_in[1];
    // d_in[2] = input_length: unused by the reference computation
    const int*   tlen   = (const int*)d_in[3];
    float* ws = (float*)d_ws;

    ctc_alpha<<<NN, 256, 0, stream>>>(pred, target, tlen, ws);
    ctc_reduce<<<1, NN, 0, stream>>>(ws, (float*)d_out);
}

// Round 6
// 217.598 us; speedup vs baseline: 3.6072x; 1.1791x over previous
//
#include <hip/hip_runtime.h>

// CTC loss forward (sum), faithful to the JAX reference.
// T=2048, N=256, C=128, L=200, S=2L+1=401.
//
// One workgroup (4 waves) per sample; wave w owns states 128w..128w+127,
// 2 per lane (s0=2*idx blank, s1=2*idx+1 label, idx=64w+lane). Intra-wave
// halo via DPP wave_shr:1 (update_dpp 'old' merges the lane-0 boundary).
// Cross-wave: strictly left->right, one boundary float per step through
// bnd[w][t] + monotonic per-wave block flags; consumers run 1 block (16
// steps) skewed, bulk-read 16 boundaries per block via 4x ds_read_b128
// broadcast. No barriers in the main loop; wave 0 never waits.
// Emissions: direct global->register, 16-deep prefetch (wave0's HBM-miss
// floor ~900cy/16 = 56cy/step); scB (class 0) is wave-uniform -> scalar.
// Log2 domain (v_exp_f32/v_log_f32 base-2 native); blank states lse2;
// skip mask folded into additive penalty pk1.

#define TT 2048
#define NN 256
#define CC 128
#define LL 200

#define K_LOG2E 1.4426950408889634f
#define K_LN2   0.6931471805599453f
#define NEGB   (-1.44e30f)   /* -1e30 * log2(e) */
#define PEN    (-2.0e30f)    /* additive 'disallowed' penalty */
#define NC4    131072u       /* NN*CC*4 bytes: stride between time rows */

__device__ __forceinline__ float max3f(float a, float b, float c) {
    float r; asm("v_max3_f32 %0, %1, %2, %3" : "=v"(r) : "v"(a), "v"(b), "v"(c)); return r;
}
__device__ __forceinline__ float med3f(float a, float b, float c) {
    float r; asm("v_med3_f32 %0, %1, %2, %3" : "=v"(r) : "v"(a), "v"(b), "v"(c)); return r;
}
__device__ __forceinline__ float min3f(float a, float b, float c) {
    float r; asm("v_min3_f32 %0, %1, %2, %3" : "=v"(r) : "v"(a), "v"(b), "v"(c)); return r;
}

// log2-domain logsumexp3 + emission: max term's exp is exactly 1.
__device__ __forceinline__ float lse3(float a0, float a1, float a2, float sc) {
    const float m   = max3f(a0, a1, a2);
    const float mid = med3f(a0, a1, a2);
    const float lo  = min3f(a0, a1, a2);
    const float e = 1.0f + __builtin_amdgcn_exp2f(mid - m)
                         + __builtin_amdgcn_exp2f(lo  - m);
    return m + __builtin_amdgcn_logf(e) + K_LOG2E * sc;
}
__device__ __forceinline__ float lse2(float a, float b, float sc) {
    const float m  = fmaxf(a, b);
    const float lo = fminf(a, b);
    const float e = 1.0f + __builtin_amdgcn_exp2f(lo - m);
    return m + __builtin_amdgcn_logf(e) + K_LOG2E * sc;
}

__global__ __launch_bounds__(256, 1)
void ctc_alpha(const float* __restrict__ pred,
               const int* __restrict__ target,
               const int* __restrict__ tlen,
               float* __restrict__ loss_ws)
{
    __shared__ float bnd[5][TT];   // [w][t]: state 128w+127 after step t; row 4 = PEN (wave0 halo)
    __shared__ int   flags[8];     // [w] = 16-step blocks completed; [7] = INT_MAX dummy

    const int tid  = threadIdx.x;
    const int wid  = tid >> 6;
    const int lane = tid & 63;
    const int n    = blockIdx.x;

    if (tid < 8) flags[tid] = (tid >= 4) ? 0x7fffffff : 0;
    for (int i = tid; i < TT; i += 256) bnd[4][i] = PEN;

    // per-state constants. Reference quirk: starts[0]=0, starts[n>0]=tlen[n-1].
    const int start = (n == 0) ? 0 : tlen[n - 1];
    const int idx   = (wid << 6) | lane;     // s0 = 2*idx (blank), s1 = 2*idx+1 (label)
    int lab1 = 0; float pk1 = PEN;
    if (idx < LL) {
        lab1 = target[start + idx];
        if (idx >= 1 && lab1 != target[start + idx - 1]) pk1 = 0.0f;   // skip allowed
    }

    // ---- alpha_0 (log2 domain): only states 0,1 (idx==0) live ----
    float al0, al1;
    {
        const float eB = pred[n * CC];
        const float eL = pred[n * CC + lab1];
        al0 = (idx == 0) ? K_LOG2E * eB : NEGB;
        al1 = (idx == 0) ? K_LOG2E * eL : NEGB;
    }
    if (lane == 63) bnd[wid][0] = al1;
    __syncthreads();   // flags/PEN-row/bnd[.][0] visible before any spin

    // ---- emission register pipeline, depth 16 (rows t..t+15 resident) ----
    const char*  pc = (const char*)pred;
    const float* bp = pred + (NN * CC) + n * CC;               // row 1, class 0 (uniform)
    uint32_t offL = (uint32_t)(NN * CC + n * CC + lab1) * 4u;  // row 1, class lab1
    float scB[16], scL[16];
#pragma unroll
    for (int ph = 0; ph < 16; ++ph) {                          // rows 1..16
        scB[ph] = *bp;  bp += NN * CC;
        scL[ph] = *(const float*)(pc + offL);  offL += NC4;
    }

    const int     pidx  = (wid == 0) ? 7 : (wid - 1);
    const float*  bndC  = (wid == 0) ? bnd[4] : bnd[wid - 1];
    float*        bndW  = bnd[wid];
    volatile int* pflag = &flags[pidx];
    int fval = *pflag;

    float bndv[16];
#define LOAD_BNDV(RB)                                                          \
    {                                                                          \
        const float4* q = (const float4*)(bndC + (RB));                        \
        const float4 q0 = q[0], q1 = q[1], q2 = q[2], q3 = q[3];               \
        bndv[0]=q0.x;  bndv[1]=q0.y;  bndv[2]=q0.z;  bndv[3]=q0.w;             \
        bndv[4]=q1.x;  bndv[5]=q1.y;  bndv[6]=q1.z;  bndv[7]=q1.w;             \
        bndv[8]=q2.x;  bndv[9]=q2.y;  bndv[10]=q2.z; bndv[11]=q2.w;            \
        bndv[12]=q3.x; bndv[13]=q3.y; bndv[14]=q3.z; bndv[15]=q3.w;            \
    }

    // One step, t = TBASE+1+PH. Halo h1 = prev lane's al1; lane0 <- bndv[PH]
    // via update_dpp's old operand (wave_shr:1 = 0x138).
#define CTC_STEP(PH, TBASE, PREF)                                              \
    {                                                                          \
        const int h1i = __builtin_amdgcn_update_dpp(                           \
            __float_as_int(bndv[PH]), __float_as_int(al1),                     \
            0x138, 0xf, 0xf, false);                                           \
        const float h1  = __int_as_float(h1i);                                 \
        const float na1 = lse3(al1, al0, h1 + pk1, scL[PH]);                   \
        const float na0 = lse2(al0, h1, scB[PH]);                              \
        al1 = na1; al0 = na0;                                                  \
        if (lane == 63) bndW[(TBASE) + 1 + (PH)] = al1;                        \
        if (PREF) {                                                            \
            scB[PH] = *bp;  bp += NN * CC;                                     \
            scL[PH] = *(const float*)(pc + offL);  offL += NC4;                \
        }                                                                      \
    }

    // main: blocks b=0..125 cover t=1..2016, prefetch rows 17..2032 (no clamp)
    for (int b = 0; b < 126; ++b) {
        const int need = b + 1;                       // bnd[16b..16b+15] written
        if (fval < need) { do { fval = *pflag; } while (fval < need); }
        asm volatile("" ::: "memory");
        LOAD_BNDV(16 * b)
        const int tb = 16 * b;
        CTC_STEP( 0, tb, 1) CTC_STEP( 1, tb, 1) CTC_STEP( 2, tb, 1) CTC_STEP( 3, tb, 1)
        CTC_STEP( 4, tb, 1) CTC_STEP( 5, tb, 1) CTC_STEP( 6, tb, 1) CTC_STEP( 7, tb, 1)
        CTC_STEP( 8, tb, 1) CTC_STEP( 9, tb, 1) CTC_STEP(10, tb, 1) CTC_STEP(11, tb, 1)
        CTC_STEP(12, tb, 1) CTC_STEP(13, tb, 1) CTC_STEP(14, tb, 1) CTC_STEP(15, tb, 1)
        asm volatile("" ::: "memory");                // bnd writes before flag post
        if (lane == 0) *(volatile int*)&flags[wid] = b + 1;
        fval = *pflag;                                // refresh; checked next block
    }

    // block 126: t=2017..2032; prefetch rows 2033..2047 (last step: none)
    {
        if (fval < 127) { do { fval = *pflag; } while (fval < 127); }
        asm volatile("" ::: "memory");
        LOAD_BNDV(2016)
        CTC_STEP( 0, 2016, 1) CTC_STEP( 1, 2016, 1) CTC_STEP( 2, 2016, 1) CTC_STEP( 3, 2016, 1)
        CTC_STEP( 4, 2016, 1) CTC_STEP( 5, 2016, 1) CTC_STEP( 6, 2016, 1) CTC_STEP( 7, 2016, 1)
        CTC_STEP( 8, 2016, 1) CTC_STEP( 9, 2016, 1) CTC_STEP(10, 2016, 1) CTC_STEP(11, 2016, 1)
        CTC_STEP(12, 2016, 1) CTC_STEP(13, 2016, 1) CTC_STEP(14, 2016, 1) CTC_STEP(15, 2016, 0)
        asm volatile("" ::: "memory");
        if (lane == 0) *(volatile int*)&flags[wid] = 127;
        fval = *pflag;
    }

    // tail: t=2033..2047 (15 steps); producer posts flag 128 after ITS tail
    {
        if (fval < 128) { do { fval = *pflag; } while (fval < 128); }
        asm volatile("" ::: "memory");
        LOAD_BNDV(2032)
        CTC_STEP( 0, 2032, 0) CTC_STEP( 1, 2032, 0) CTC_STEP( 2, 2032, 0) CTC_STEP( 3, 2032, 0)
        CTC_STEP( 4, 2032, 0) CTC_STEP( 5, 2032, 0) CTC_STEP( 6, 2032, 0) CTC_STEP( 7, 2032, 0)
        CTC_STEP( 8, 2032, 0) CTC_STEP( 9, 2032, 0) CTC_STEP(10, 2032, 0) CTC_STEP(11, 2032, 0)
        CTC_STEP(12, 2032, 0) CTC_STEP(13, 2032, 0) CTC_STEP(14, 2032, 0)
        asm volatile("" ::: "memory");
        if (lane == 0) *(volatile int*)&flags[wid] = 128;
    }
#undef CTC_STEP
#undef LOAD_BNDV

    // loss: states 399 (wave3 lane7 al1) and 400 (wave3 lane8 al0)
    const float A = __shfl(al1, 7, 64);
    const float B = __shfl(al0, 8, 64);
    if (wid == 3 && lane == 0) {
        const float m  = fmaxf(A, B);
        const float ls = m + __builtin_amdgcn_logf(
            __builtin_amdgcn_exp2f(A - m) + __builtin_amdgcn_exp2f(B - m));
        loss_ws[n] = -ls * K_LN2;   // back to natural log
    }
}

__global__ void ctc_reduce(const float* __restrict__ ws, float* __restrict__ out)
{
    const int tid = threadIdx.x;   // 256 threads, 4 waves
    float v = ws[tid];
    v += __shfl_down(v, 32);
    v += __shfl_down(v, 16);
    v += __shfl_down(v, 8);
    v += __shfl_down(v, 4);
    v += __shfl_down(v, 2);
    v += __shfl_down(v, 1);
    __shared__ float p[4];
    if ((tid & 63) == 0) p[tid >> 6] = v;
    __syncthreads();
    if (tid == 0) out[0] = (p[0] + p[1]) + (p[2] + p[3]);
}

extern "C" void kernel_launch(void* const* d_in, const int* in_sizes, int n_in,
                              void* d_out, int out_size, void* d_ws, size_t ws_size,
                              hipStream_t stream)
{
    const float* pred   = (const float*)d_in[0];
    const int*   target = (const int*)d_in[1];
    // d_in[2] = input_length: unused by the reference computation
    const int*   tlen   = (const int*)d_in[3];
    float* ws = (float*)d_ws;

    ctc_alpha<<<NN, 256, 0, stream>>>(pred, target, tlen, ws);
    ctc_reduce<<<1, NN, 0, stream>>>(ws, (float*)d_out);
}